// Round 5
// baseline (517.753 us; speedup 1.0000x reference)
//
#include <hip/hip_runtime.h>
#include <hip/hip_bf16.h>

// CrossAttention (B=4,T=2048,C=1024,H=16,D=64), fp32 in/out, bf16 MFMA compute.
// Pipeline: cvt(q,k,v)+transpose-cvt(W*) -> fused QKV proj GEMM -> flash attn -> out GEMM.
// R1: +XCD bijective swizzle (T1/m204) on gemm+attn grids; Ps barrier -> wave-local
//     lgkmcnt(0) (Ps rows are wave-private).
// R2: attn K/V 2-phase double-buffer (issue-early stage, one drain barrier per tile).
// R3: attn LDS XOR-swizzle (T2 both-sides: pre-swizzled global src + swizzled read,
//     chunk ^= row&7); T5 setprio around attn MFMA; prep batched.
// R4: QKV GEMMs fused to one dispatch (uniform select); T13 defer-max (THR=8) in
//     attn online softmax; rcp epilogue. 5 dispatches total.

#define B_ 4
#define T_ 2048
#define C_ 1024
#define H_ 16
#define D_ 64
#define M_ (B_*T_)   // 8192 tokens

typedef __attribute__((ext_vector_type(4))) float f32x4;
typedef __attribute__((ext_vector_type(8))) short short8;

__device__ __forceinline__ unsigned short f2bf(float f) {
  unsigned u = __float_as_uint(f);
  u = (u + 0x7fffu + ((u >> 16) & 1u)) >> 16;   // RNE
  return (unsigned short)u;
}

// async global->LDS, 16B per lane. lds ptr must be wave-uniform (lane*16 auto).
__device__ __forceinline__ void gload_lds16(const void* g, void* l) {
  __builtin_amdgcn_global_load_lds(
      (__attribute__((address_space(1))) void*)(g),
      (__attribute__((address_space(3))) void*)(l), 16, 0, 0);
}

// ---------------- prep kernels (batched) ----------------
__global__ __launch_bounds__(256) void cvt3_f32_bf16(const float* __restrict__ s0,
                                                     const float* __restrict__ s1,
                                                     const float* __restrict__ s2,
                                                     unsigned short* __restrict__ o0,
                                                     unsigned short* __restrict__ o1,
                                                     unsigned short* __restrict__ o2,
                                                     int n4) {
  const float* s = (blockIdx.y == 0) ? s0 : (blockIdx.y == 1) ? s1 : s2;
  unsigned short* d = (blockIdx.y == 0) ? o0 : (blockIdx.y == 1) ? o1 : o2;
  int i = blockIdx.x * 256 + threadIdx.x;
  if (i < n4) {
    float4 v = ((const float4*)s)[i];
    ushort4 o = { f2bf(v.x), f2bf(v.y), f2bf(v.z), f2bf(v.w) };
    ((ushort4*)d)[i] = o;
  }
}

// W [K=1024][N=1024] f32 (x @ W form) -> WT [N][K] bf16 (B^T GEMM form). 4 weights.
__global__ __launch_bounds__(256) void transpose_cvt4(const float* __restrict__ W0,
                                                      const float* __restrict__ W1,
                                                      const float* __restrict__ W2,
                                                      const float* __restrict__ W3,
                                                      unsigned short* __restrict__ T0,
                                                      unsigned short* __restrict__ T1,
                                                      unsigned short* __restrict__ T2,
                                                      unsigned short* __restrict__ T3) {
  __shared__ float tile[64][65];
  const int z = blockIdx.z;
  const float* W = (z == 0) ? W0 : (z == 1) ? W1 : (z == 2) ? W2 : W3;
  unsigned short* WT = (z == 0) ? T0 : (z == 1) ? T1 : (z == 2) ? T2 : T3;
  const int tr = blockIdx.y * 64;   // k block
  const int tc = blockIdx.x * 64;   // n block
  const int t = threadIdx.x;
  const int cg = (t & 15) * 4;
  const int rw = t >> 4;
#pragma unroll
  for (int it = 0; it < 4; ++it) {
    int r = it * 16 + rw;
    float4 v = *(const float4*)(W + (size_t)(tr + r) * C_ + tc + cg);
    tile[r][cg] = v.x; tile[r][cg + 1] = v.y; tile[r][cg + 2] = v.z; tile[r][cg + 3] = v.w;
  }
  __syncthreads();
#pragma unroll
  for (int it = 0; it < 4; ++it) {
    int n = it * 16 + rw;
    ushort4 o = { f2bf(tile[cg][n]), f2bf(tile[cg + 1][n]),
                  f2bf(tile[cg + 2][n]), f2bf(tile[cg + 3][n]) };
    *(ushort4*)(WT + (size_t)(tc + n) * C_ + tr + cg) = o;
  }
}

// ---------------- GEMM core (m97 structure, frozen) ----------------
// acc[4][4] = A[128,1024] x BT[128,1024]^T tile at (bm,bn); both row-major [rows][K].
__device__ __forceinline__ void gemm_core(const unsigned short* __restrict__ A,
                                          const unsigned short* __restrict__ BT,
                                          int bm, int bn, int wid, int lane,
                                          unsigned short* As, unsigned short* Bs,
                                          f32x4 acc[4][4]) {
  const int wr = wid >> 1, wc = wid & 1;       // 2x2 wave grid, 64x64 per wave
  const int lr = lane & 15, lk = lane >> 4;
  for (int k0 = 0; k0 < C_; k0 += 64) {
    __syncthreads();                            // prev-iter frag reads done
#pragma unroll
    for (int it = 0; it < 4; ++it) {            // A tile 128x64 bf16, linear LDS
      int wo = it * 256 + wid * 64;
      int o = wo + lane;
      gload_lds16(A + (size_t)(bm * 128 + (o >> 3)) * C_ + k0 + (o & 7) * 8, As + wo * 8);
    }
#pragma unroll
    for (int it = 0; it < 4; ++it) {
      int wo = it * 256 + wid * 64;
      int o = wo + lane;
      gload_lds16(BT + (size_t)(bn * 128 + (o >> 3)) * C_ + k0 + (o & 7) * 8, Bs + wo * 8);
    }
    __syncthreads();                            // drains vmcnt(0) before barrier

    short8 af[2][4], bf[2][4];
#pragma unroll
    for (int kc = 0; kc < 2; ++kc) {
#pragma unroll
      for (int mi = 0; mi < 4; ++mi)
        af[kc][mi] = *(const short8*)(As + (wr * 64 + mi * 16 + lr) * 64 + kc * 32 + lk * 8);
#pragma unroll
      for (int ni = 0; ni < 4; ++ni)
        bf[kc][ni] = *(const short8*)(Bs + (wc * 64 + ni * 16 + lr) * 64 + kc * 32 + lk * 8);
    }
#pragma unroll
    for (int kc = 0; kc < 2; ++kc)
#pragma unroll
      for (int mi = 0; mi < 4; ++mi)
#pragma unroll
        for (int ni = 0; ni < 4; ++ni)
          acc[mi][ni] = __builtin_amdgcn_mfma_f32_16x16x32_bf16(af[kc][mi], bf[kc][ni],
                                                                acc[mi][ni], 0, 0, 0);
  }
}

// Fused Q/K/V projection: grid (512, 3); y selects operand set (uniform branch).
// y=0,1 -> bf16 [B,H,T,D] (Q,K); y=2 -> bf16 [B,H,D,T] (V^T).
__global__ __launch_bounds__(256) void gemm_qkv(const unsigned short* __restrict__ qb,
                                                const unsigned short* __restrict__ kb,
                                                const unsigned short* __restrict__ vb,
                                                const unsigned short* __restrict__ wqt,
                                                const unsigned short* __restrict__ wkt,
                                                const unsigned short* __restrict__ wvt,
                                                const float* __restrict__ bq,
                                                const float* __restrict__ bk,
                                                const float* __restrict__ bv,
                                                unsigned short* __restrict__ Qh,
                                                unsigned short* __restrict__ Kh,
                                                unsigned short* __restrict__ VTh) {
  __shared__ unsigned short As[128 * 64];
  __shared__ unsigned short Bs[128 * 64];
  const int y = blockIdx.y;
  const unsigned short* A  = (y == 0) ? qb  : (y == 1) ? kb  : vb;
  const unsigned short* BT = (y == 0) ? wqt : (y == 1) ? wkt : wvt;
  const float* bias        = (y == 0) ? bq  : (y == 1) ? bk  : bv;
  unsigned short* O        = (y == 0) ? Qh  : (y == 1) ? Kh  : VTh;
  const bool vt = (y == 2);
  // T1 bijective XCD swizzle: nwg=512, 512%8==0, chunk=64 per XCD.
  const int id = blockIdx.x;
  const int wk = (id & 7) * 64 + (id >> 3);
  const int bn = wk & 7;          // C_/128 = 8
  const int bm = wk >> 3;         // M_/128 = 64
  const int wid = threadIdx.x >> 6, lane = threadIdx.x & 63;
  const int wr = wid >> 1, wc = wid & 1;
  const int lr = lane & 15, lk = lane >> 4;
  f32x4 acc[4][4] = {};
  gemm_core(A, BT, bm, bn, wid, lane, As, Bs, acc);

  float bvv[4];
#pragma unroll
  for (int ni = 0; ni < 4; ++ni) bvv[ni] = bias[bn * 128 + wc * 64 + ni * 16 + lr];
#pragma unroll
  for (int mi = 0; mi < 4; ++mi)
#pragma unroll
    for (int ni = 0; ni < 4; ++ni) {
      int n = bn * 128 + wc * 64 + ni * 16 + lr;   // channel = h*64+d
      int h = n >> 6, d = n & 63;
#pragma unroll
      for (int j = 0; j < 4; ++j) {
        int m = bm * 128 + wr * 64 + mi * 16 + lk * 4 + j;  // token = b*T+t
        int b = m >> 11, tt = m & (T_ - 1);
        size_t idx = vt ? ((size_t)(b * H_ + h) * D_ + d) * T_ + tt   // 4 j's contiguous
                        : ((size_t)(b * H_ + h) * T_ + tt) * D_ + d;
        O[idx] = f2bf(acc[mi][ni][j] + bvv[ni]);
      }
    }
}

// Output projection: out f32 [M,C] -> d_out.
__global__ __launch_bounds__(256) void gemm_out(const unsigned short* __restrict__ A,
                                                const unsigned short* __restrict__ BT,
                                                const float* __restrict__ bias,
                                                float* __restrict__ O) {
  __shared__ unsigned short As[128 * 64];
  __shared__ unsigned short Bs[128 * 64];
  const int id = blockIdx.x;
  const int wk = (id & 7) * 64 + (id >> 3);
  const int bn = wk & 7;
  const int bm = wk >> 3;
  const int wid = threadIdx.x >> 6, lane = threadIdx.x & 63;
  const int wr = wid >> 1, wc = wid & 1;
  const int lr = lane & 15, lk = lane >> 4;
  f32x4 acc[4][4] = {};
  gemm_core(A, BT, bm, bn, wid, lane, As, Bs, acc);

  float bvv[4];
#pragma unroll
  for (int ni = 0; ni < 4; ++ni) bvv[ni] = bias[bn * 128 + wc * 64 + ni * 16 + lr];
#pragma unroll
  for (int mi = 0; mi < 4; ++mi)
#pragma unroll
    for (int ni = 0; ni < 4; ++ni) {
      int n = bn * 128 + wc * 64 + ni * 16 + lr;
#pragma unroll
      for (int j = 0; j < 4; ++j) {
        int m = bm * 128 + wr * 64 + mi * 16 + lk * 4 + j;
        O[(size_t)m * C_ + n] = acc[mi][ni][j] + bvv[ni];
      }
    }
}

// ---------------- flash attention ----------------
// 1D grid 2048 blocks XCD-swizzled. 4 waves x 16 q-rows, KBLK=64.
// Q/K [B,H,T,D], V as VT [B,H,D,T]. K/V double-buffered (2-phase pipeline).
// LDS tiles XOR-swizzled (physical chunk = logical ^ (row&7); linear LDS dest,
// pre-swizzled global src). T13 defer-max with THR=8 (natural-log units).
__global__ __launch_bounds__(256) void attn_fwd(const unsigned short* __restrict__ Qg,
                                                const unsigned short* __restrict__ Kg,
                                                const unsigned short* __restrict__ Vg,
                                                unsigned short* __restrict__ Y) {
  __shared__ unsigned short Qs[64 * 64];
  __shared__ unsigned short Ks[2][64 * 64];
  __shared__ unsigned short Vs[2][64 * 64];   // VT tile: [d=64][t=64]
  __shared__ unsigned short Ps[64 * 72];      // +8 pad: wave-private rows
  // T1 swizzle: nwg=2048, chunk=256 per XCD -> one XCD holds 8 heads' K/V.
  const int id = blockIdx.x;
  const int wk = (id & 7) * 256 + (id >> 3);
  const int bh = wk >> 5;                     // B_*H_ = 64
  const int qt = wk & 31;                     // T_/64 = 32
  const int b = bh >> 4, h = bh & 15;
  const int t = threadIdx.x;
  const int wid = t >> 6, lane = t & 63;
  const int lr = lane & 15, lk = lane >> 4;
  const size_t hoff = (size_t)bh * T_ * D_;
  const unsigned short* Qh = Qg + hoff + (size_t)qt * 64 * D_;
  const unsigned short* Kh = Kg + hoff;
  const unsigned short* Vh = Vg + hoff;       // [D][T]
  const int NT = T_ / 64;                     // 32 k-tiles

  // lane covers LDS slot o = wo+lane -> physical (row=o>>3, chunk=o&7);
  // fetch global logical chunk (o&7)^(row&7)  (both-sides involution, rule 21).
  auto stage = [&](int bfi, int kt) {
    const unsigned short* Ksrc = Kh + (size_t)kt * 64 * D_;
#pragma unroll
    for (int it = 0; it < 2; ++it) {
      int wo = it * 256 + wid * 64;
      int o = wo + lane;
      int r = o >> 3, c = (o & 7) ^ (r & 7);
      gload_lds16(Ksrc + (size_t)r * D_ + c * 8, Ks[bfi] + wo * 8);
      gload_lds16(Vh + (size_t)r * T_ + kt * 64 + c * 8, Vs[bfi] + wo * 8);
    }
  };

  // prologue: Q tile + first K/V tile in flight together (Q swizzled identically)
#pragma unroll
  for (int it = 0; it < 2; ++it) {
    int wo = it * 256 + wid * 64;
    int o = wo + lane;
    int r = o >> 3, c = (o & 7) ^ (r & 7);
    gload_lds16(Qh + (size_t)r * D_ + c * 8, Qs + wo * 8);
  }
  stage(0, 0);
  __syncthreads();                            // drains vmcnt(0): Q + tile0 ready
  short8 qf[2];
#pragma unroll
  for (int kc = 0; kc < 2; ++kc)              // logical chunk kc*4+lk, row wid*16+lr
    qf[kc] = *(const short8*)(Qs + (wid * 16 + lr) * 64 + (((kc * 4 + lk) ^ (lr & 7)) * 8));

  f32x4 yacc[4] = {};
  float mrow[4], lsum[4];
#pragma unroll
  for (int i = 0; i < 4; ++i) { mrow[i] = -1e30f; lsum[i] = 0.f; }
  const float SCL = 0.125f;                   // 1/sqrt(D)
  const float L2E = 1.44269504088896f;

  int cur = 0;
  for (int kt = 0; kt < NT; ++kt) {
    // issue-early: next tile's loads fly under this tile's compute.
    // buf^1 was last READ at iter kt-1; end-of-(kt-1) __syncthreads ordered
    // those reads (lgkmcnt drain, all waves) before this overwrite.
    if (kt + 1 < NT) stage(cur ^ 1, kt + 1);

    // S[16,64] per wave = Q @ K^T   (rows of Ks: nt*16+lr -> row&7 == lr&7)
    f32x4 sacc[4] = {};
    __builtin_amdgcn_s_setprio(1);
#pragma unroll
    for (int kc = 0; kc < 2; ++kc)
#pragma unroll
      for (int nt = 0; nt < 4; ++nt) {
        short8 kf = *(const short8*)(Ks[cur] + (nt * 16 + lr) * 64 +
                                     (((kc * 4 + lk) ^ (lr & 7)) * 8));
        sacc[nt] = __builtin_amdgcn_mfma_f32_16x16x32_bf16(qf[kc], kf, sacc[nt], 0, 0, 0);
      }
    __builtin_amdgcn_s_setprio(0);

    // online softmax, T13 defer-max: lane holds rows lk*4+i, col lr+nt*16.
    float mx[4];
    int need = 0;
#pragma unroll
    for (int i = 0; i < 4; ++i) {
      float m0 = fmaxf(fmaxf(sacc[0][i], sacc[1][i]), fmaxf(sacc[2][i], sacc[3][i]));
      m0 = fmaxf(m0, __shfl_xor(m0, 1, 16));
      m0 = fmaxf(m0, __shfl_xor(m0, 2, 16));
      m0 = fmaxf(m0, __shfl_xor(m0, 4, 16));
      m0 = fmaxf(m0, __shfl_xor(m0, 8, 16));
      mx[i] = m0 * SCL;
      need |= (mx[i] - mrow[i] > 8.0f);       // P bounded by e^8 if skipped
    }
    if (__any(need)) {                        // wave-uniform rescale path
#pragma unroll
      for (int i = 0; i < 4; ++i) {
        float mn = fmaxf(mrow[i], mx[i]);
        float esc = exp2f((mrow[i] - mn) * L2E);
        mrow[i] = mn;
        lsum[i] *= esc;
        yacc[0][i] *= esc; yacc[1][i] *= esc;
        yacc[2][i] *= esc; yacc[3][i] *= esc;
      }
    }
    float rs[4] = {0.f, 0.f, 0.f, 0.f};
#pragma unroll
    for (int nt = 0; nt < 4; ++nt)
#pragma unroll
      for (int i = 0; i < 4; ++i) {
        float p = exp2f(sacc[nt][i] * (SCL * L2E) - mrow[i] * L2E);
        rs[i] += p;
        Ps[(wid * 16 + lk * 4 + i) * 72 + nt * 16 + lr] = f2bf(p);
      }
#pragma unroll
    for (int i = 0; i < 4; ++i) {
      float s = rs[i];
      s += __shfl_xor(s, 1, 16);
      s += __shfl_xor(s, 2, 16);
      s += __shfl_xor(s, 4, 16);
      s += __shfl_xor(s, 8, 16);
      lsum[i] += s;
    }
    // Ps rows [16*wid,16*wid+16) are wave-private: wave-local LDS ordering is
    // sufficient (consumer below is a ds_read -> ordered by "memory" clobber).
    asm volatile("s_waitcnt lgkmcnt(0)" ::: "memory");

    // y[16,64] += P @ V  (B-fragments from VT rows, swizzled like K)
    __builtin_amdgcn_s_setprio(1);
#pragma unroll
    for (int kc = 0; kc < 2; ++kc) {
      short8 pa = *(const short8*)(Ps + (wid * 16 + lr) * 72 + kc * 32 + lk * 8);
#pragma unroll
      for (int nt = 0; nt < 4; ++nt) {
        short8 vf = *(const short8*)(Vs[cur] + (nt * 16 + lr) * 64 +
                                     (((kc * 4 + lk) ^ (lr & 7)) * 8));
        yacc[nt] = __builtin_amdgcn_mfma_f32_16x16x32_bf16(pa, vf, yacc[nt], 0, 0, 0);
      }
    }
    __builtin_amdgcn_s_setprio(0);

    __syncthreads();   // drain: next tile's stage complete + this tile's reads done
    cur ^= 1;
  }

#pragma unroll
  for (int i = 0; i < 4; ++i) {
    float rinv = __builtin_amdgcn_rcpf(lsum[i]);   // bf16 out: 1-ulp rcp is plenty
#pragma unroll
    for (int nt = 0; nt < 4; ++nt) {
      int row = qt * 64 + wid * 16 + lk * 4 + i;
      int col = h * D_ + nt * 16 + lr;
      Y[((size_t)b * T_ + row) * C_ + col] = f2bf(yacc[nt][i] * rinv);
    }
  }
}

// ---------------- launch ----------------
extern "C" void kernel_launch(void* const* d_in, const int* in_sizes, int n_in,
                              void* d_out, int out_size, void* d_ws, size_t ws_size,
                              hipStream_t stream) {
  const float* q  = (const float*)d_in[0];
  const float* k  = (const float*)d_in[1];
  const float* v  = (const float*)d_in[2];
  const float* Wq = (const float*)d_in[3];
  const float* bq = (const float*)d_in[4];
  const float* Wk = (const float*)d_in[5];
  const float* bk = (const float*)d_in[6];
  const float* Wv = (const float*)d_in[7];
  const float* bv = (const float*)d_in[8];
  const float* Wo = (const float*)d_in[9];
  const float* bo = (const float*)d_in[10];

  char* ws = (char*)d_ws;
  const size_t S1 = (size_t)M_ * C_ * 2;   // 16.78 MB activation bf16
  const size_t SW = (size_t)C_ * C_ * 2;   // 2.10 MB weight bf16
  unsigned short* qb  = (unsigned short*)(ws);
  unsigned short* kb  = (unsigned short*)(ws + S1);
  unsigned short* vb  = (unsigned short*)(ws + 2 * S1);
  unsigned short* wqt = (unsigned short*)(ws + 3 * S1);
  unsigned short* wkt = (unsigned short*)(ws + 3 * S1 + SW);
  unsigned short* wvt = (unsigned short*)(ws + 3 * S1 + 2 * SW);
  unsigned short* wot = (unsigned short*)(ws + 3 * S1 + 3 * SW);
  unsigned short* Qh  = (unsigned short*)(ws + 3 * S1 + 4 * SW);
  unsigned short* Kh  = (unsigned short*)(ws + 4 * S1 + 4 * SW);
  unsigned short* VTh = (unsigned short*)(ws + 5 * S1 + 4 * SW);
  unsigned short* Yw  = (unsigned short*)(ws + 6 * S1 + 4 * SW);
  // total ws use: 7*S1 + 4*SW ~= 126 MB

  const int n4 = M_ * C_ / 4;
  cvt3_f32_bf16<<<dim3(n4 / 256, 3), 256, 0, stream>>>(q, k, v, qb, kb, vb, n4);
  transpose_cvt4<<<dim3(16, 16, 4), 256, 0, stream>>>(Wq, Wk, Wv, Wo,
                                                      wqt, wkt, wvt, wot);

  const int ngemm = (C_ / 128) * (M_ / 128);   // 512
  gemm_qkv<<<dim3(ngemm, 3), 256, 0, stream>>>(qb, kb, vb, wqt, wkt, wvt,
                                               bq, bk, bv, Qh, Kh, VTh);

  attn_fwd<<<(T_ / 64) * B_ * H_, 256, 0, stream>>>(Qh, Kh, VTh, Yw);

  gemm_out<<<ngemm, 256, 0, stream>>>(Yw, wot, bo, (float*)d_out);
}

// Round 7
// 432.673 us; speedup vs baseline: 1.1966x; 1.1966x over previous
//
#include <hip/hip_runtime.h>
#include <hip/hip_bf16.h>

// CrossAttention (B=4,T=2048,C=1024,H=16,D=64), fp32 in/out, bf16 MFMA compute.
// Pipeline: prep(cvt q/k/v + transpose-cvt W*) -> fused QKV GEMM -> flash attn -> out GEMM.
// R1: XCD bijective swizzle (T1/m204); wave-private Ps ordering via lgkmcnt(0).
// R2: attn K/V 2-phase double-buffer (issue-early stage, one drain barrier/tile).
// R3: attn LDS XOR-swizzle (T2 both-sides); T5 setprio; prep batched.
// R4: fused QKV GEMM dispatch; T13 defer-max; rcp epilogue.
// R5 (vs measured 517.8us / attn 267.8us MfmaUtil 11% VALUBusy 62% Occ 30.5%):
//     swapped QK^T (mfma(kf,qf) -> lane owns ONE q-row: scalar mrow/lsum, 4 shfl
//     total), cvt_pk_bf16 P-pack + 4x ds_write_b64, Ps 8KB XOR-swizzled, Q staged
//     into Ps union -> LDS 40960B = 4 blocks/CU.  [unmeasured; re-audited R6]
// R6: prep fused to ONE dispatch (24576 cvt blocks + 1024 transpose blocks, 1D
//     grid, block-uniform branch). attn/GEMMs byte-identical to R5.

#define B_ 4
#define T_ 2048
#define C_ 1024
#define H_ 16
#define D_ 64
#define M_ (B_*T_)   // 8192 tokens

typedef __attribute__((ext_vector_type(4))) float f32x4;
typedef __attribute__((ext_vector_type(8))) short short8;

__device__ __forceinline__ unsigned short f2bf(float f) {
  unsigned u = __float_as_uint(f);
  u = (u + 0x7fffu + ((u >> 16) & 1u)) >> 16;   // RNE
  return (unsigned short)u;
}

// pack two f32 -> (bf16,bf16) in one u32, RNE (gfx950 v_cvt_pk_bf16_f32)
__device__ __forceinline__ unsigned cvtpk_bf16(float lo, float hi) {
  unsigned r;
  asm("v_cvt_pk_bf16_f32 %0, %1, %2" : "=v"(r) : "v"(lo), "v"(hi));
  return r;
}

// async global->LDS, 16B per lane. lds ptr must be wave-uniform (lane*16 auto).
__device__ __forceinline__ void gload_lds16(const void* g, void* l) {
  __builtin_amdgcn_global_load_lds(
      (__attribute__((address_space(1))) void*)(g),
      (__attribute__((address_space(3))) void*)(l), 16, 0, 0);
}

// ---------------- prep: one dispatch ----------------
// blocks [0, 24576): f32->bf16 cvt of q/k/v (arr = id>>13, chunk = id&8191;
//   n4 = 8192*256 exactly, no bounds check needed).
// blocks [24576, 25600): 64x64 transpose-cvt tiles of the 4 weights.
__global__ __launch_bounds__(256) void prep_all(const float* __restrict__ q,
                                                const float* __restrict__ k,
                                                const float* __restrict__ v,
                                                const float* __restrict__ W0,
                                                const float* __restrict__ W1,
                                                const float* __restrict__ W2,
                                                const float* __restrict__ W3,
                                                unsigned short* __restrict__ qb,
                                                unsigned short* __restrict__ kb,
                                                unsigned short* __restrict__ vb,
                                                unsigned short* __restrict__ T0,
                                                unsigned short* __restrict__ T1,
                                                unsigned short* __restrict__ T2,
                                                unsigned short* __restrict__ T3) {
  __shared__ float tile[64][65];
  const int id = blockIdx.x;
  if (id < 24576) {                 // cvt path: 3 x 8192 blocks
    const int arr = id >> 13;
    const int blk = id & 8191;
    const float* s = (arr == 0) ? q : (arr == 1) ? k : v;
    unsigned short* d = (arr == 0) ? qb : (arr == 1) ? kb : vb;
    int i = blk * 256 + threadIdx.x;
    float4 x = ((const float4*)s)[i];
    ushort4 o = { f2bf(x.x), f2bf(x.y), f2bf(x.z), f2bf(x.w) };
    ((ushort4*)d)[i] = o;
  } else {                          // transpose path: 4 x 256 blocks
    const int tid = id - 24576;
    const int z = tid >> 8;
    const int tl = tid & 255;
    const float* W = (z == 0) ? W0 : (z == 1) ? W1 : (z == 2) ? W2 : W3;
    unsigned short* WT = (z == 0) ? T0 : (z == 1) ? T1 : (z == 2) ? T2 : T3;
    const int tr = (tl >> 4) * 64;  // k block
    const int tc = (tl & 15) * 64;  // n block
    const int t = threadIdx.x;
    const int cg = (t & 15) * 4;
    const int rw = t >> 4;
#pragma unroll
    for (int it = 0; it < 4; ++it) {
      int r = it * 16 + rw;
      float4 x = *(const float4*)(W + (size_t)(tr + r) * C_ + tc + cg);
      tile[r][cg] = x.x; tile[r][cg + 1] = x.y; tile[r][cg + 2] = x.z; tile[r][cg + 3] = x.w;
    }
    __syncthreads();
#pragma unroll
    for (int it = 0; it < 4; ++it) {
      int n = it * 16 + rw;
      ushort4 o = { f2bf(tile[cg][n]), f2bf(tile[cg + 1][n]),
                    f2bf(tile[cg + 2][n]), f2bf(tile[cg + 3][n]) };
      *(ushort4*)(WT + (size_t)(tc + n) * C_ + tr + cg) = o;
    }
  }
}

// ---------------- GEMM core (m97 structure, frozen) ----------------
__device__ __forceinline__ void gemm_core(const unsigned short* __restrict__ A,
                                          const unsigned short* __restrict__ BT,
                                          int bm, int bn, int wid, int lane,
                                          unsigned short* As, unsigned short* Bs,
                                          f32x4 acc[4][4]) {
  const int wr = wid >> 1, wc = wid & 1;       // 2x2 wave grid, 64x64 per wave
  const int lr = lane & 15, lk = lane >> 4;
  for (int k0 = 0; k0 < C_; k0 += 64) {
    __syncthreads();                            // prev-iter frag reads done
#pragma unroll
    for (int it = 0; it < 4; ++it) {            // A tile 128x64 bf16, linear LDS
      int wo = it * 256 + wid * 64;
      int o = wo + lane;
      gload_lds16(A + (size_t)(bm * 128 + (o >> 3)) * C_ + k0 + (o & 7) * 8, As + wo * 8);
    }
#pragma unroll
    for (int it = 0; it < 4; ++it) {
      int wo = it * 256 + wid * 64;
      int o = wo + lane;
      gload_lds16(BT + (size_t)(bn * 128 + (o >> 3)) * C_ + k0 + (o & 7) * 8, Bs + wo * 8);
    }
    __syncthreads();                            // drains vmcnt(0) before barrier

    short8 af[2][4], bf[2][4];
#pragma unroll
    for (int kc = 0; kc < 2; ++kc) {
#pragma unroll
      for (int mi = 0; mi < 4; ++mi)
        af[kc][mi] = *(const short8*)(As + (wr * 64 + mi * 16 + lr) * 64 + kc * 32 + lk * 8);
#pragma unroll
      for (int ni = 0; ni < 4; ++ni)
        bf[kc][ni] = *(const short8*)(Bs + (wc * 64 + ni * 16 + lr) * 64 + kc * 32 + lk * 8);
    }
#pragma unroll
    for (int kc = 0; kc < 2; ++kc)
#pragma unroll
      for (int mi = 0; mi < 4; ++mi)
#pragma unroll
        for (int ni = 0; ni < 4; ++ni)
          acc[mi][ni] = __builtin_amdgcn_mfma_f32_16x16x32_bf16(af[kc][mi], bf[kc][ni],
                                                                acc[mi][ni], 0, 0, 0);
  }
}

// Fused Q/K/V projection: grid (512, 3); y selects operand set (uniform branch).
__global__ __launch_bounds__(256) void gemm_qkv(const unsigned short* __restrict__ qb,
                                                const unsigned short* __restrict__ kb,
                                                const unsigned short* __restrict__ vb,
                                                const unsigned short* __restrict__ wqt,
                                                const unsigned short* __restrict__ wkt,
                                                const unsigned short* __restrict__ wvt,
                                                const float* __restrict__ bq,
                                                const float* __restrict__ bk,
                                                const float* __restrict__ bv,
                                                unsigned short* __restrict__ Qh,
                                                unsigned short* __restrict__ Kh,
                                                unsigned short* __restrict__ VTh) {
  __shared__ unsigned short As[128 * 64];
  __shared__ unsigned short Bs[128 * 64];
  const int y = blockIdx.y;
  const unsigned short* A  = (y == 0) ? qb  : (y == 1) ? kb  : vb;
  const unsigned short* BT = (y == 0) ? wqt : (y == 1) ? wkt : wvt;
  const float* bias        = (y == 0) ? bq  : (y == 1) ? bk  : bv;
  unsigned short* O        = (y == 0) ? Qh  : (y == 1) ? Kh  : VTh;
  const bool vt = (y == 2);
  const int id = blockIdx.x;
  const int wk = (id & 7) * 64 + (id >> 3);
  const int bn = wk & 7;          // C_/128 = 8
  const int bm = wk >> 3;         // M_/128 = 64
  const int wid = threadIdx.x >> 6, lane = threadIdx.x & 63;
  const int wr = wid >> 1, wc = wid & 1;
  const int lr = lane & 15, lk = lane >> 4;
  f32x4 acc[4][4] = {};
  gemm_core(A, BT, bm, bn, wid, lane, As, Bs, acc);

  float bvv[4];
#pragma unroll
  for (int ni = 0; ni < 4; ++ni) bvv[ni] = bias[bn * 128 + wc * 64 + ni * 16 + lr];
#pragma unroll
  for (int mi = 0; mi < 4; ++mi)
#pragma unroll
    for (int ni = 0; ni < 4; ++ni) {
      int n = bn * 128 + wc * 64 + ni * 16 + lr;   // channel = h*64+d
      int h = n >> 6, d = n & 63;
#pragma unroll
      for (int j = 0; j < 4; ++j) {
        int m = bm * 128 + wr * 64 + mi * 16 + lk * 4 + j;  // token = b*T+t
        int b = m >> 11, tt = m & (T_ - 1);
        size_t idx = vt ? ((size_t)(b * H_ + h) * D_ + d) * T_ + tt   // 4 j's contiguous
                        : ((size_t)(b * H_ + h) * T_ + tt) * D_ + d;
        O[idx] = f2bf(acc[mi][ni][j] + bvv[ni]);
      }
    }
}

// Output projection: out f32 [M,C] -> d_out.
__global__ __launch_bounds__(256) void gemm_out(const unsigned short* __restrict__ A,
                                                const unsigned short* __restrict__ BT,
                                                const float* __restrict__ bias,
                                                float* __restrict__ O) {
  __shared__ unsigned short As[128 * 64];
  __shared__ unsigned short Bs[128 * 64];
  const int id = blockIdx.x;
  const int wk = (id & 7) * 64 + (id >> 3);
  const int bn = wk & 7;
  const int bm = wk >> 3;
  const int wid = threadIdx.x >> 6, lane = threadIdx.x & 63;
  const int wr = wid >> 1, wc = wid & 1;
  const int lr = lane & 15, lk = lane >> 4;
  f32x4 acc[4][4] = {};
  gemm_core(A, BT, bm, bn, wid, lane, As, Bs, acc);

  float bvv[4];
#pragma unroll
  for (int ni = 0; ni < 4; ++ni) bvv[ni] = bias[bn * 128 + wc * 64 + ni * 16 + lr];
#pragma unroll
  for (int mi = 0; mi < 4; ++mi)
#pragma unroll
    for (int ni = 0; ni < 4; ++ni) {
      int n = bn * 128 + wc * 64 + ni * 16 + lr;
#pragma unroll
      for (int j = 0; j < 4; ++j) {
        int m = bm * 128 + wr * 64 + mi * 16 + lk * 4 + j;
        O[(size_t)m * C_ + n] = acc[mi][ni][j] + bvv[ni];
      }
    }
}

// ---------------- flash attention (R5: swapped QK^T, lane-local softmax) --------
// grid 2048 XCD-swizzled. 4 waves x 16 q-rows, KBLK=64. Q/K [B,H,T,D], V [B,H,D,T].
// sacc = mfma(kf, qf): lane holds S^T[k=nt*16+lk*4+reg][q=wid*16+lr] -> one q-row/lane.
// yacc = mfma(pa, vf): row=q lk*4+reg, col=d nt*16+lr.
__global__ __launch_bounds__(256) void attn_fwd(const unsigned short* __restrict__ Qg,
                                                const unsigned short* __restrict__ Kg,
                                                const unsigned short* __restrict__ Vg,
                                                unsigned short* __restrict__ Y) {
  __shared__ unsigned short Ks[2][64 * 64];
  __shared__ unsigned short Vs[2][64 * 64];   // VT tile: [d=64][t=64]
  __shared__ unsigned short Ps[64 * 64];      // P tile; doubles as Q staging (union)
  // LDS total = 40960 B exactly -> 4 blocks/CU.
  const int id = blockIdx.x;
  const int wk = (id & 7) * 256 + (id >> 3);
  const int bh = wk >> 5;                     // B_*H_ = 64
  const int qt = wk & 31;                     // T_/64 = 32
  const int b = bh >> 4, h = bh & 15;
  const int t = threadIdx.x;
  const int wid = t >> 6, lane = t & 63;
  const int lr = lane & 15, lk = lane >> 4;
  const size_t hoff = (size_t)bh * T_ * D_;
  const unsigned short* Qh = Qg + hoff + (size_t)qt * 64 * D_;
  const unsigned short* Kh = Kg + hoff;
  const unsigned short* Vh = Vg + hoff;       // [D][T]
  const int NT = T_ / 64;                     // 32 k-tiles

  // both-sides involution (rule 21): linear LDS dest, global src chunk ^= row&7.
  auto stage = [&](int bfi, int kt) {
    const unsigned short* Ksrc = Kh + (size_t)kt * 64 * D_;
#pragma unroll
    for (int it = 0; it < 2; ++it) {
      int wo = it * 256 + wid * 64;
      int o = wo + lane;
      int r = o >> 3, c = (o & 7) ^ (r & 7);
      gload_lds16(Ksrc + (size_t)r * D_ + c * 8, Ks[bfi] + wo * 8);
      gload_lds16(Vh + (size_t)r * T_ + kt * 64 + c * 8, Vs[bfi] + wo * 8);
    }
  };

  // prologue: Q tile staged into Ps region (swizzled) + first K/V tile
#pragma unroll
  for (int it = 0; it < 2; ++it) {
    int wo = it * 256 + wid * 64;
    int o = wo + lane;
    int r = o >> 3, c = (o & 7) ^ (r & 7);
    gload_lds16(Qh + (size_t)r * D_ + c * 8, Ps + wo * 8);
  }
  stage(0, 0);
  __syncthreads();                            // drains vmcnt(0): Q + tile0 ready
  short8 qf[2];
#pragma unroll
  for (int kc = 0; kc < 2; ++kc)              // B-frag: row = q-row wid*16+lr
    qf[kc] = *(const short8*)(Ps + (wid * 16 + lr) * 64 + (((kc * 4 + lk) ^ (lr & 7)) * 8));
  // qf must be in regs before Ps is reused for P (wave-private rows; wave-local wait)
  asm volatile("s_waitcnt lgkmcnt(0)" ::: "memory");

  f32x4 yacc[4] = {};
  float mrow = -1e30f, lsum = 0.f;            // scalar state: one q-row per lane
  const float SCL = 0.125f;                   // 1/sqrt(D)
  const float L2E = 1.44269504088896f;
  const float C1 = SCL * L2E;

  int cur = 0;
  for (int kt = 0; kt < NT; ++kt) {
    if (kt + 1 < NT) stage(cur ^ 1, kt + 1);  // issue-early; hazards per R2 audit

    // S^T[64k,16q] per wave = mfma(K-frag, Q-frag) — same LDS reads as before
    f32x4 sacc[4] = {};
    __builtin_amdgcn_s_setprio(1);
#pragma unroll
    for (int kc = 0; kc < 2; ++kc)
#pragma unroll
      for (int nt = 0; nt < 4; ++nt) {
        short8 kf = *(const short8*)(Ks[cur] + (nt * 16 + lr) * 64 +
                                     (((kc * 4 + lk) ^ (lr & 7)) * 8));
        sacc[nt] = __builtin_amdgcn_mfma_f32_16x16x32_bf16(kf, qf[kc], sacc[nt], 0, 0, 0);
      }
    __builtin_amdgcn_s_setprio(0);

    // lane-local softmax for q-row wid*16+lr; k = nt*16 + lk*4 + reg
    float m0 = fmaxf(fmaxf(sacc[0][0], sacc[0][1]), fmaxf(sacc[0][2], sacc[0][3]));
#pragma unroll
    for (int nt = 1; nt < 4; ++nt)
      m0 = fmaxf(m0, fmaxf(fmaxf(sacc[nt][0], sacc[nt][1]),
                           fmaxf(sacc[nt][2], sacc[nt][3])));
    m0 = fmaxf(m0, __shfl_xor(m0, 16, 64));   // reduce over lk (same lr)
    m0 = fmaxf(m0, __shfl_xor(m0, 32, 64));
    float mx = m0 * SCL;
    if (__any(mx - mrow > 8.0f)) {            // T13 defer-max (P <= e^8 if skipped)
      float mn = fmaxf(mrow, mx);
      float esc = exp2f((mrow - mn) * L2E);
      mrow = mn;
      lsum *= esc;
      float e0 = __shfl(esc, 4 * lk + 0, 16);
      float e1 = __shfl(esc, 4 * lk + 1, 16);
      float e2 = __shfl(esc, 4 * lk + 2, 16);
      float e3 = __shfl(esc, 4 * lk + 3, 16);
#pragma unroll
      for (int nt = 0; nt < 4; ++nt) {
        yacc[nt][0] *= e0; yacc[nt][1] *= e1;
        yacc[nt][2] *= e2; yacc[nt][3] *= e3;
      }
    }
    float ml2 = mrow * L2E;
    float rs = 0.f;
#pragma unroll
    for (int nt = 0; nt < 4; ++nt) {
      float p0 = exp2f(sacc[nt][0] * C1 - ml2);
      float p1 = exp2f(sacc[nt][1] * C1 - ml2);
      float p2 = exp2f(sacc[nt][2] * C1 - ml2);
      float p3 = exp2f(sacc[nt][3] * C1 - ml2);
      rs += (p0 + p1) + (p2 + p3);
      uint2 pv;                               // memory order p0,p1,p2,p3 (LE)
      pv.x = cvtpk_bf16(p0, p1);
      pv.y = cvtpk_bf16(p2, p3);
      // P row = q-row; logical granule 2nt+(lk>>1), phys ^= lr&7 (matches reads)
      *(uint2*)(Ps + (wid * 16 + lr) * 64 +
                (((2 * nt + (lk >> 1)) ^ (lr & 7)) * 8 + (lk & 1) * 4)) = pv;
    }
    rs += __shfl_xor(rs, 16, 64);
    rs += __shfl_xor(rs, 32, 64);
    lsum += rs;
    // Ps rows [16w,16w+16) wave-private: wave-local wait orders writes before reads
    asm volatile("s_waitcnt lgkmcnt(0)" ::: "memory");

    // y[16,64] += P @ V
    __builtin_amdgcn_s_setprio(1);
#pragma unroll
    for (int kc = 0; kc < 2; ++kc) {
      short8 pa = *(const short8*)(Ps + (wid * 16 + lr) * 64 +
                                   (((kc * 4 + lk) ^ (lr & 7)) * 8));
#pragma unroll
      for (int nt = 0; nt < 4; ++nt) {
        short8 vf = *(const short8*)(Vs[cur] + (nt * 16 + lr) * 64 +
                                     (((kc * 4 + lk) ^ (lr & 7)) * 8));
        yacc[nt] = __builtin_amdgcn_mfma_f32_16x16x32_bf16(pa, vf, yacc[nt], 0, 0, 0);
      }
    }
    __builtin_amdgcn_s_setprio(0);

    __syncthreads();   // drain: next tile's stage complete + this tile's reads done
    cur ^= 1;
  }

  float rinv = __builtin_amdgcn_rcpf(lsum);   // q-row wid*16+lr
  float r0 = __shfl(rinv, 4 * lk + 0, 16);
  float r1 = __shfl(rinv, 4 * lk + 1, 16);
  float r2 = __shfl(rinv, 4 * lk + 2, 16);
  float r3 = __shfl(rinv, 4 * lk + 3, 16);
#pragma unroll
  for (int nt = 0; nt < 4; ++nt) {
    int row = qt * 64 + wid * 16 + lk * 4;
    int col = h * D_ + nt * 16 + lr;
    size_t base = ((size_t)b * T_ + row) * C_ + col;
    Y[base]          = f2bf(yacc[nt][0] * r0);
    Y[base + C_]     = f2bf(yacc[nt][1] * r1);
    Y[base + 2 * C_] = f2bf(yacc[nt][2] * r2);
    Y[base + 3 * C_] = f2bf(yacc[nt][3] * r3);
  }
}

// ---------------- launch ----------------
extern "C" void kernel_launch(void* const* d_in, const int* in_sizes, int n_in,
                              void* d_out, int out_size, void* d_ws, size_t ws_size,
                              hipStream_t stream) {
  const float* q  = (const float*)d_in[0];
  const float* k  = (const float*)d_in[1];
  const float* v  = (const float*)d_in[2];
  const float* Wq = (const float*)d_in[3];
  const float* bq = (const float*)d_in[4];
  const float* Wk = (const float*)d_in[5];
  const float* bk = (const float*)d_in[6];
  const float* Wv = (const float*)d_in[7];
  const float* bv = (const float*)d_in[8];
  const float* Wo = (const float*)d_in[9];
  const float* bo = (const float*)d_in[10];

  char* ws = (char*)d_ws;
  const size_t S1 = (size_t)M_ * C_ * 2;   // 16.78 MB activation bf16
  const size_t SW = (size_t)C_ * C_ * 2;   // 2.10 MB weight bf16
  unsigned short* qb  = (unsigned short*)(ws);
  unsigned short* kb  = (unsigned short*)(ws + S1);
  unsigned short* vb  = (unsigned short*)(ws + 2 * S1);
  unsigned short* wqt = (unsigned short*)(ws + 3 * S1);
  unsigned short* wkt = (unsigned short*)(ws + 3 * S1 + SW);
  unsigned short* wvt = (unsigned short*)(ws + 3 * S1 + 2 * SW);
  unsigned short* wot = (unsigned short*)(ws + 3 * S1 + 3 * SW);
  unsigned short* Qh  = (unsigned short*)(ws + 3 * S1 + 4 * SW);
  unsigned short* Kh  = (unsigned short*)(ws + 4 * S1 + 4 * SW);
  unsigned short* VTh = (unsigned short*)(ws + 5 * S1 + 4 * SW);
  unsigned short* Yw  = (unsigned short*)(ws + 6 * S1 + 4 * SW);
  // total ws use: 7*S1 + 4*SW ~= 126 MB

  prep_all<<<25600, 256, 0, stream>>>(q, k, v, Wq, Wk, Wv, Wo,
                                      qb, kb, vb, wqt, wkt, wvt, wot);

  const int ngemm = (C_ / 128) * (M_ / 128);   // 512
  gemm_qkv<<<dim3(ngemm, 3), 256, 0, stream>>>(qb, kb, vb, wqt, wkt, wvt,
                                               bq, bk, bv, Qh, Kh, VTh);

  attn_fwd<<<(T_ / 64) * B_ * H_, 256, 0, stream>>>(Qh, Kh, VTh, Yw);

  gemm_out<<<ngemm, 256, 0, stream>>>(Yw, wot, bo, (float*)d_out);
}

// Round 9
// 419.107 us; speedup vs baseline: 1.2354x; 1.0324x over previous
//
#include <hip/hip_runtime.h>
#include <hip/hip_bf16.h>

// CrossAttention (B=4,T=2048,C=1024,H=16,D=64), fp32 in/out, bf16 MFMA compute.
// Pipeline: prep(cvt q/k/v + transpose-cvt W*) -> fused QKV GEMM -> flash attn -> out GEMM.
// R1: XCD bijective swizzle (T1/m204). R2: attn K/V double-buffer, issue-early.
// R3: attn LDS XOR-swizzle (both-sides involution); T5 setprio. R4: fused QKV GEMM;
// T13 defer-max; rcp epilogue. R5: swapped QK^T (lane owns one q-row), cvt_pk P-pack,
// Ps 8KB XOR-swizzled + Q-staging union -> 40KB LDS. R6: prep fused to one dispatch.
// R7 (vs measured 432.7us; attn 176.3us MfmaUtil 16.9 VALUBusy 72.3 Occ 38.6):
//     attn k-split 8-wave blocks: wave (wq,kh) does k-half kh of each tile for
//     q-rows wq*16..+15 -> per-lane softmax VALU halves (8 exp2/tile). Independent
//     (m,l,y) per half; exact online-softmax merge at epilogue via Ks/Vs LDS reuse.
//     Occupancy ceiling 16->32 waves/CU. GEMMs/prep frozen (m97-structure ceiling).
// R8: broker timeout; R7 re-audited (staging geometry, fragment algebra, P-granule
//     round-trip, kh-privacy under XOR, shfl segments, merge) and resubmitted as-is.

#define B_ 4
#define T_ 2048
#define C_ 1024
#define H_ 16
#define D_ 64
#define M_ (B_*T_)   // 8192 tokens

typedef __attribute__((ext_vector_type(4))) float f32x4;
typedef __attribute__((ext_vector_type(8))) short short8;

__device__ __forceinline__ unsigned short f2bf(float f) {
  unsigned u = __float_as_uint(f);
  u = (u + 0x7fffu + ((u >> 16) & 1u)) >> 16;   // RNE
  return (unsigned short)u;
}

// pack two f32 -> (bf16,bf16) in one u32, RNE (gfx950 v_cvt_pk_bf16_f32)
__device__ __forceinline__ unsigned cvtpk_bf16(float lo, float hi) {
  unsigned r;
  asm("v_cvt_pk_bf16_f32 %0, %1, %2" : "=v"(r) : "v"(lo), "v"(hi));
  return r;
}

// async global->LDS, 16B per lane. lds ptr must be wave-uniform (lane*16 auto).
__device__ __forceinline__ void gload_lds16(const void* g, void* l) {
  __builtin_amdgcn_global_load_lds(
      (__attribute__((address_space(1))) void*)(g),
      (__attribute__((address_space(3))) void*)(l), 16, 0, 0);
}

// ---------------- prep: one dispatch ----------------
__global__ __launch_bounds__(256) void prep_all(const float* __restrict__ q,
                                                const float* __restrict__ k,
                                                const float* __restrict__ v,
                                                const float* __restrict__ W0,
                                                const float* __restrict__ W1,
                                                const float* __restrict__ W2,
                                                const float* __restrict__ W3,
                                                unsigned short* __restrict__ qb,
                                                unsigned short* __restrict__ kb,
                                                unsigned short* __restrict__ vb,
                                                unsigned short* __restrict__ T0,
                                                unsigned short* __restrict__ T1,
                                                unsigned short* __restrict__ T2,
                                                unsigned short* __restrict__ T3) {
  __shared__ float tile[64][65];
  const int id = blockIdx.x;
  if (id < 24576) {                 // cvt path: 3 x 8192 blocks
    const int arr = id >> 13;
    const int blk = id & 8191;
    const float* s = (arr == 0) ? q : (arr == 1) ? k : v;
    unsigned short* d = (arr == 0) ? qb : (arr == 1) ? kb : vb;
    int i = blk * 256 + threadIdx.x;
    float4 x = ((const float4*)s)[i];
    ushort4 o = { f2bf(x.x), f2bf(x.y), f2bf(x.z), f2bf(x.w) };
    ((ushort4*)d)[i] = o;
  } else {                          // transpose path: 4 x 256 blocks
    const int tid = id - 24576;
    const int z = tid >> 8;
    const int tl = tid & 255;
    const float* W = (z == 0) ? W0 : (z == 1) ? W1 : (z == 2) ? W2 : W3;
    unsigned short* WT = (z == 0) ? T0 : (z == 1) ? T1 : (z == 2) ? T2 : T3;
    const int tr = (tl >> 4) * 64;  // k block
    const int tc = (tl & 15) * 64;  // n block
    const int t = threadIdx.x;
    const int cg = (t & 15) * 4;
    const int rw = t >> 4;
#pragma unroll
    for (int it = 0; it < 4; ++it) {
      int r = it * 16 + rw;
      float4 x = *(const float4*)(W + (size_t)(tr + r) * C_ + tc + cg);
      tile[r][cg] = x.x; tile[r][cg + 1] = x.y; tile[r][cg + 2] = x.z; tile[r][cg + 3] = x.w;
    }
    __syncthreads();
#pragma unroll
    for (int it = 0; it < 4; ++it) {
      int n = it * 16 + rw;
      ushort4 o = { f2bf(tile[cg][n]), f2bf(tile[cg + 1][n]),
                    f2bf(tile[cg + 2][n]), f2bf(tile[cg + 3][n]) };
      *(ushort4*)(WT + (size_t)(tc + n) * C_ + tr + cg) = o;
    }
  }
}

// ---------------- GEMM core (m97 structure, frozen) ----------------
__device__ __forceinline__ void gemm_core(const unsigned short* __restrict__ A,
                                          const unsigned short* __restrict__ BT,
                                          int bm, int bn, int wid, int lane,
                                          unsigned short* As, unsigned short* Bs,
                                          f32x4 acc[4][4]) {
  const int wr = wid >> 1, wc = wid & 1;       // 2x2 wave grid, 64x64 per wave
  const int lr = lane & 15, lk = lane >> 4;
  for (int k0 = 0; k0 < C_; k0 += 64) {
    __syncthreads();                            // prev-iter frag reads done
#pragma unroll
    for (int it = 0; it < 4; ++it) {            // A tile 128x64 bf16, linear LDS
      int wo = it * 256 + wid * 64;
      int o = wo + lane;
      gload_lds16(A + (size_t)(bm * 128 + (o >> 3)) * C_ + k0 + (o & 7) * 8, As + wo * 8);
    }
#pragma unroll
    for (int it = 0; it < 4; ++it) {
      int wo = it * 256 + wid * 64;
      int o = wo + lane;
      gload_lds16(BT + (size_t)(bn * 128 + (o >> 3)) * C_ + k0 + (o & 7) * 8, Bs + wo * 8);
    }
    __syncthreads();                            // drains vmcnt(0) before barrier

    short8 af[2][4], bf[2][4];
#pragma unroll
    for (int kc = 0; kc < 2; ++kc) {
#pragma unroll
      for (int mi = 0; mi < 4; ++mi)
        af[kc][mi] = *(const short8*)(As + (wr * 64 + mi * 16 + lr) * 64 + kc * 32 + lk * 8);
#pragma unroll
      for (int ni = 0; ni < 4; ++ni)
        bf[kc][ni] = *(const short8*)(Bs + (wc * 64 + ni * 16 + lr) * 64 + kc * 32 + lk * 8);
    }
#pragma unroll
    for (int kc = 0; kc < 2; ++kc)
#pragma unroll
      for (int mi = 0; mi < 4; ++mi)
#pragma unroll
        for (int ni = 0; ni < 4; ++ni)
          acc[mi][ni] = __builtin_amdgcn_mfma_f32_16x16x32_bf16(af[kc][mi], bf[kc][ni],
                                                                acc[mi][ni], 0, 0, 0);
  }
}

// Fused Q/K/V projection: grid (512, 3); y selects operand set (uniform branch).
__global__ __launch_bounds__(256) void gemm_qkv(const unsigned short* __restrict__ qb,
                                                const unsigned short* __restrict__ kb,
                                                const unsigned short* __restrict__ vb,
                                                const unsigned short* __restrict__ wqt,
                                                const unsigned short* __restrict__ wkt,
                                                const unsigned short* __restrict__ wvt,
                                                const float* __restrict__ bq,
                                                const float* __restrict__ bk,
                                                const float* __restrict__ bv,
                                                unsigned short* __restrict__ Qh,
                                                unsigned short* __restrict__ Kh,
                                                unsigned short* __restrict__ VTh) {
  __shared__ unsigned short As[128 * 64];
  __shared__ unsigned short Bs[128 * 64];
  const int y = blockIdx.y;
  const unsigned short* A  = (y == 0) ? qb  : (y == 1) ? kb  : vb;
  const unsigned short* BT = (y == 0) ? wqt : (y == 1) ? wkt : wvt;
  const float* bias        = (y == 0) ? bq  : (y == 1) ? bk  : bv;
  unsigned short* O        = (y == 0) ? Qh  : (y == 1) ? Kh  : VTh;
  const bool vt = (y == 2);
  const int id = blockIdx.x;
  const int wk = (id & 7) * 64 + (id >> 3);
  const int bn = wk & 7;          // C_/128 = 8
  const int bm = wk >> 3;         // M_/128 = 64
  const int wid = threadIdx.x >> 6, lane = threadIdx.x & 63;
  const int wr = wid >> 1, wc = wid & 1;
  const int lr = lane & 15, lk = lane >> 4;
  f32x4 acc[4][4] = {};
  gemm_core(A, BT, bm, bn, wid, lane, As, Bs, acc);

  float bvv[4];
#pragma unroll
  for (int ni = 0; ni < 4; ++ni) bvv[ni] = bias[bn * 128 + wc * 64 + ni * 16 + lr];
#pragma unroll
  for (int mi = 0; mi < 4; ++mi)
#pragma unroll
    for (int ni = 0; ni < 4; ++ni) {
      int n = bn * 128 + wc * 64 + ni * 16 + lr;   // channel = h*64+d
      int h = n >> 6, d = n & 63;
#pragma unroll
      for (int j = 0; j < 4; ++j) {
        int m = bm * 128 + wr * 64 + mi * 16 + lk * 4 + j;  // token = b*T+t
        int b = m >> 11, tt = m & (T_ - 1);
        size_t idx = vt ? ((size_t)(b * H_ + h) * D_ + d) * T_ + tt   // 4 j's contiguous
                        : ((size_t)(b * H_ + h) * T_ + tt) * D_ + d;
        O[idx] = f2bf(acc[mi][ni][j] + bvv[ni]);
      }
    }
}

// Output projection: out f32 [M,C] -> d_out.
__global__ __launch_bounds__(256) void gemm_out(const unsigned short* __restrict__ A,
                                                const unsigned short* __restrict__ BT,
                                                const float* __restrict__ bias,
                                                float* __restrict__ O) {
  __shared__ unsigned short As[128 * 64];
  __shared__ unsigned short Bs[128 * 64];
  const int id = blockIdx.x;
  const int wk = (id & 7) * 64 + (id >> 3);
  const int bn = wk & 7;
  const int bm = wk >> 3;
  const int wid = threadIdx.x >> 6, lane = threadIdx.x & 63;
  const int wr = wid >> 1, wc = wid & 1;
  const int lr = lane & 15, lk = lane >> 4;
  f32x4 acc[4][4] = {};
  gemm_core(A, BT, bm, bn, wid, lane, As, Bs, acc);

  float bvv[4];
#pragma unroll
  for (int ni = 0; ni < 4; ++ni) bvv[ni] = bias[bn * 128 + wc * 64 + ni * 16 + lr];
#pragma unroll
  for (int mi = 0; mi < 4; ++mi)
#pragma unroll
    for (int ni = 0; ni < 4; ++ni) {
      int n = bn * 128 + wc * 64 + ni * 16 + lr;
#pragma unroll
      for (int j = 0; j < 4; ++j) {
        int m = bm * 128 + wr * 64 + mi * 16 + lk * 4 + j;
        O[(size_t)m * C_ + n] = acc[mi][ni][j] + bvv[ni];
      }
    }
}

// ---------------- flash attention (R7: 8-wave k-split) ----------------
// grid 2048 XCD-swizzled, 512 threads. Wave (wq=wid&3, kh=wid>>2): q-rows
// wq*16..+15, k-half kh (32 of 64 k per tile). Independent (m,l,yacc) per half;
// exact merge at epilogue. Q/K [B,H,T,D], V [B,H,D,T]. All LDS XOR-swizzled
// (granule ^= row&7, row&7 == lr&7 for every access).
__global__ __launch_bounds__(512) void attn_fwd(const unsigned short* __restrict__ Qg,
                                                const unsigned short* __restrict__ Kg,
                                                const unsigned short* __restrict__ Vg,
                                                unsigned short* __restrict__ Y) {
  __shared__ unsigned short Ks[2][64 * 64];
  __shared__ unsigned short Vs[2][64 * 64];   // VT tile: [d=64][t=64]
  __shared__ unsigned short Ps[64 * 64];      // P tile; doubles as Q staging
  // LDS total = 40960 B -> 4 blocks/CU x 8 waves = 32 waves/CU ceiling.
  const int id = blockIdx.x;
  const int wk = (id & 7) * 256 + (id >> 3);
  const int bh = wk >> 5;                     // B_*H_ = 64
  const int qt = wk & 31;                     // T_/64 = 32
  const int b = bh >> 4, h = bh & 15;
  const int t = threadIdx.x;
  const int wid = t >> 6, lane = t & 63;
  const int wq = wid & 3, kh = wid >> 2;      // q-subtile, k-half
  const int lr = lane & 15, lk = lane >> 4;
  const size_t hoff = (size_t)bh * T_ * D_;
  const unsigned short* Qh = Qg + hoff + (size_t)qt * 64 * D_;
  const unsigned short* Kh = Kg + hoff;
  const unsigned short* Vh = Vg + hoff;       // [D][T]
  const int NT = T_ / 64;                     // 32 k-tiles

  // this thread's staging slot (512 slots cover one 8KB tile exactly)
  const int o = wid * 64 + lane;
  const int sr = o >> 3, sc = (o & 7) ^ ((o >> 3) & 7);
  const int sbase = wid * 512;                // wave-uniform short offset

  auto stage = [&](int bfi, int kt) {
    gload_lds16(Kh + (size_t)kt * 64 * D_ + (size_t)sr * D_ + sc * 8, Ks[bfi] + sbase);
    gload_lds16(Vh + (size_t)sr * T_ + kt * 64 + sc * 8, Vs[bfi] + sbase);
  };

  // prologue: Q into Ps (swizzled) + first K/V tile
  gload_lds16(Qh + (size_t)sr * D_ + sc * 8, Ps + sbase);
  stage(0, 0);
  __syncthreads();                            // Q + tile0 ready
  short8 qf[2];
#pragma unroll
  for (int kc = 0; kc < 2; ++kc)              // B-frag: row = q-row wq*16+lr
    qf[kc] = *(const short8*)(Ps + (wq * 16 + lr) * 64 + (((kc * 4 + lk) ^ (lr & 7)) * 8));
  __syncthreads();                            // ALL waves' qf in regs before P-writes

  f32x4 yacc[4] = {};
  float mrow = -1e30f, lsum = 0.f;            // per-lane state for its q-row, k-half
  const float SCL = 0.125f;                   // 1/sqrt(D)
  const float L2E = 1.44269504088896f;
  const float C1 = SCL * L2E;

  int cur = 0;
  for (int kt = 0; kt < NT; ++kt) {
    if (kt + 1 < NT) stage(cur ^ 1, kt + 1);  // issue-early

    // S^T[32k x 16q] = mfma(K-frag rows kh*32.., Q-frag)
    f32x4 sacc[2] = {};
    __builtin_amdgcn_s_setprio(1);
#pragma unroll
    for (int kc = 0; kc < 2; ++kc)
#pragma unroll
      for (int ntl = 0; ntl < 2; ++ntl) {
        short8 kf = *(const short8*)(Ks[cur] + (kh * 32 + ntl * 16 + lr) * 64 +
                                     (((kc * 4 + lk) ^ (lr & 7)) * 8));
        sacc[ntl] = __builtin_amdgcn_mfma_f32_16x16x32_bf16(kf, qf[kc], sacc[ntl], 0, 0, 0);
      }
    __builtin_amdgcn_s_setprio(0);

    // lane-local softmax (8 values: k = kh*32 + ntl*16 + lk*4 + reg)
    float m0 = fmaxf(fmaxf(sacc[0][0], sacc[0][1]), fmaxf(sacc[0][2], sacc[0][3]));
    m0 = fmaxf(m0, fmaxf(fmaxf(sacc[1][0], sacc[1][1]), fmaxf(sacc[1][2], sacc[1][3])));
    m0 = fmaxf(m0, __shfl_xor(m0, 16, 64));   // reduce over lk (same lr)
    m0 = fmaxf(m0, __shfl_xor(m0, 32, 64));
    float mx = m0 * SCL;
    if (__any(mx - mrow > 8.0f)) {            // T13 defer-max (P <= e^8 if skipped)
      float mn = fmaxf(mrow, mx);
      float esc = exp2f((mrow - mn) * L2E);
      mrow = mn;
      lsum *= esc;
      float e0 = __shfl(esc, 4 * lk + 0, 16);
      float e1 = __shfl(esc, 4 * lk + 1, 16);
      float e2 = __shfl(esc, 4 * lk + 2, 16);
      float e3 = __shfl(esc, 4 * lk + 3, 16);
#pragma unroll
      for (int nt = 0; nt < 4; ++nt) {
        yacc[nt][0] *= e0; yacc[nt][1] *= e1;
        yacc[nt][2] *= e2; yacc[nt][3] *= e3;
      }
    }
    float ml2 = mrow * L2E;
    float rs = 0.f;
#pragma unroll
    for (int ntl = 0; ntl < 2; ++ntl) {
      float p0 = exp2f(sacc[ntl][0] * C1 - ml2);
      float p1 = exp2f(sacc[ntl][1] * C1 - ml2);
      float p2 = exp2f(sacc[ntl][2] * C1 - ml2);
      float p3 = exp2f(sacc[ntl][3] * C1 - ml2);
      rs += (p0 + p1) + (p2 + p3);
      uint2 pv;                               // memory order p0..p3 (LE)
      pv.x = cvtpk_bf16(p0, p1);
      pv.y = cvtpk_bf16(p2, p3);
      // logical granule kh*4 + ntl*2 + (lk>>1); phys ^= lr&7 (matches pa read)
      *(uint2*)(Ps + (wq * 16 + lr) * 64 +
                (((kh * 4 + ntl * 2 + (lk >> 1)) ^ (lr & 7)) * 8 + (lk & 1) * 4)) = pv;
    }
    rs += __shfl_xor(rs, 16, 64);
    rs += __shfl_xor(rs, 32, 64);
    lsum += rs;
    // this wave reads ONLY granules kh*4..kh*4+3 of rows wq*16.. -> wave-private
    asm volatile("s_waitcnt lgkmcnt(0)" ::: "memory");

    // y[16q x 64d] += P(k-half) @ V(k-half): one K=32 MFMA step
    __builtin_amdgcn_s_setprio(1);
    short8 pa = *(const short8*)(Ps + (wq * 16 + lr) * 64 +
                                 (((kh * 4 + lk) ^ (lr & 7)) * 8));
#pragma unroll
    for (int nt = 0; nt < 4; ++nt) {
      short8 vf = *(const short8*)(Vs[cur] + (nt * 16 + lr) * 64 +
                                   (((kh * 4 + lk) ^ (lr & 7)) * 8));
      yacc[nt] = __builtin_amdgcn_mfma_f32_16x16x32_bf16(pa, vf, yacc[nt], 0, 0, 0);
    }
    __builtin_amdgcn_s_setprio(0);

    __syncthreads();   // next tile staged + this tile's reads done
    cur ^= 1;
  }

  // ---- merge k-halves (exact online-softmax merge), then store ----
  float* yb  = (float*)Ks;                    // 16 KB: kh=1 waves' yacc
  float* sml = (float*)Vs;                    // m at [0..63], l at [64..127]
  if (kh == 1) {
    if (lk == 0) { sml[wq * 16 + lr] = mrow; sml[64 + wq * 16 + lr] = lsum; }
#pragma unroll
    for (int nt = 0; nt < 4; ++nt)
      *(f32x4*)&yb[(wq * 64 + lane) * 16 + nt * 4] = yacc[nt];
  }
  __syncthreads();
  if (kh == 0) {
    float m2 = sml[wq * 16 + lr], l2 = sml[64 + wq * 16 + lr];
    float mf = fmaxf(mrow, m2);
    float a  = exp2f((mrow - mf) * L2E);
    float bb = exp2f((m2 - mf) * L2E);
    float rv = __builtin_amdgcn_rcpf(a * lsum + bb * l2);
    float ar = a * rv, br = bb * rv;
    float a0 = __shfl(ar, 4 * lk + 0, 16), b0 = __shfl(br, 4 * lk + 0, 16);
    float a1 = __shfl(ar, 4 * lk + 1, 16), b1 = __shfl(br, 4 * lk + 1, 16);
    float a2 = __shfl(ar, 4 * lk + 2, 16), b2 = __shfl(br, 4 * lk + 2, 16);
    float a3 = __shfl(ar, 4 * lk + 3, 16), b3 = __shfl(br, 4 * lk + 3, 16);
#pragma unroll
    for (int nt = 0; nt < 4; ++nt) {
      f32x4 y2 = *(f32x4*)&yb[(wq * 64 + lane) * 16 + nt * 4];
      int row = qt * 64 + wq * 16 + lk * 4;
      int col = h * D_ + nt * 16 + lr;
      size_t base = ((size_t)b * T_ + row) * C_ + col;
      Y[base]          = f2bf(a0 * yacc[nt][0] + b0 * y2[0]);
      Y[base + C_]     = f2bf(a1 * yacc[nt][1] + b1 * y2[1]);
      Y[base + 2 * C_] = f2bf(a2 * yacc[nt][2] + b2 * y2[2]);
      Y[base + 3 * C_] = f2bf(a3 * yacc[nt][3] + b3 * y2[3]);
    }
  }
}

// ---------------- launch ----------------
extern "C" void kernel_launch(void* const* d_in, const int* in_sizes, int n_in,
                              void* d_out, int out_size, void* d_ws, size_t ws_size,
                              hipStream_t stream) {
  const float* q  = (const float*)d_in[0];
  const float* k  = (const float*)d_in[1];
  const float* v  = (const float*)d_in[2];
  const float* Wq = (const float*)d_in[3];
  const float* bq = (const float*)d_in[4];
  const float* Wk = (const float*)d_in[5];
  const float* bk = (const float*)d_in[6];
  const float* Wv = (const float*)d_in[7];
  const float* bv = (const float*)d_in[8];
  const float* Wo = (const float*)d_in[9];
  const float* bo = (const float*)d_in[10];

  char* ws = (char*)d_ws;
  const size_t S1 = (size_t)M_ * C_ * 2;   // 16.78 MB activation bf16
  const size_t SW = (size_t)C_ * C_ * 2;   // 2.10 MB weight bf16
  unsigned short* qb  = (unsigned short*)(ws);
  unsigned short* kb  = (unsigned short*)(ws + S1);
  unsigned short* vb  = (unsigned short*)(ws + 2 * S1);
  unsigned short* wqt = (unsigned short*)(ws + 3 * S1);
  unsigned short* wkt = (unsigned short*)(ws + 3 * S1 + SW);
  unsigned short* wvt = (unsigned short*)(ws + 3 * S1 + 2 * SW);
  unsigned short* wot = (unsigned short*)(ws + 3 * S1 + 3 * SW);
  unsigned short* Qh  = (unsigned short*)(ws + 3 * S1 + 4 * SW);
  unsigned short* Kh  = (unsigned short*)(ws + 4 * S1 + 4 * SW);
  unsigned short* VTh = (unsigned short*)(ws + 5 * S1 + 4 * SW);
  unsigned short* Yw  = (unsigned short*)(ws + 6 * S1 + 4 * SW);
  // total ws use: 7*S1 + 4*SW ~= 126 MB

  prep_all<<<25600, 256, 0, stream>>>(q, k, v, Wq, Wk, Wv, Wo,
                                      qb, kb, vb, wqt, wkt, wvt, wot);

  const int ngemm = (C_ / 128) * (M_ / 128);   // 512
  gemm_qkv<<<dim3(ngemm, 3), 256, 0, stream>>>(qb, kb, vb, wqt, wkt, wvt,
                                               bq, bk, bv, Qh, Kh, VTh);

  attn_fwd<<<(T_ / 64) * B_ * H_, 512, 0, stream>>>(Qh, Kh, VTh, Yw);

  gemm_out<<<ngemm, 256, 0, stream>>>(Yw, wot, bo, (float*)d_out);
}